// Round 6
// baseline (76.028 us; speedup 1.0000x reference)
//
#include <hip/hip_runtime.h>

// FlexPool BFP quantize: NCHW (64,256,56,56) fp32.
// Per (n,h,w): E = floor(log2(max_c |x|)), ulp = 2^(E-2) (mantissa_bits=3),
// q = clip(rint(x/ulp), -7, 7) * ulp; 0 if the channel block is all-zero.
//
// Streaming, read-once/write-once, nontemporal. 512-thread blocks, tile =
// 128 hw positions (global hw indexing across n), so each wave instruction
// covers 2 contiguous 512 B segments. v[16] register-resident channels.

#define N_   64
#define C_   256
#define HW_  3136                  // 56*56
#define TILE_ 128                  // hw positions per block
#define NPOS (N_ * HW_)            // 200704 total (n,hw) positions
#define NBLK (NPOS / TILE_)        // 1568 blocks

typedef float f4 __attribute__((ext_vector_type(4)));

__device__ __forceinline__ void po2_scales(float amax, float& u, float& r) {
    // u = 2^(E-2), r = 2^(2-E) with E = floor(log2(amax)); 0 if amax == 0.
    u = 0.f; r = 0.f;
    if (amax > 0.f) {
        const int be = (int)(__float_as_uint(amax) >> 23);   // biased exponent
        if (be >= 3) {
            u = __uint_as_float((unsigned)(be - 2) << 23);
            r = __uint_as_float((unsigned)(256 - be) << 23);
        } else {
            // denormal / ultra-tiny amax (unreachable for N(0,1) data)
            const unsigned b2 = __float_as_uint(amax * 0x1.0p+64f);
            const int E = (int)(b2 >> 23) - 191;             // -127 - 64
            u = exp2f((float)(E - 2));
            r = exp2f((float)(2 - E));
        }
    }
}

__global__ __launch_bounds__(512)
void bfp_quant_kernel(const float* __restrict__ in, float* __restrict__ out) {
    const int t    = threadIdx.x;
    const int q    = t & 31;     // f4 slot -> tile-local hw offsets q*4..q*4+3
    const int crow = t >> 5;     // 0..15: channel-row group
    const int w    = t >> 6;     // wave id 0..7

    // global hw position of my float4 (may cross n boundaries per-lane)
    const int g0 = blockIdx.x * TILE_ + q * 4;
    const int n  = g0 / HW_;                       // compile-time magic div
    const int hw = g0 - n * HW_;                   // multiple of 4 -> f4 never straddles n
    const int base = n * (C_ * HW_) + hw;          // < 2^26, int ok

    __shared__ f4 pw[8][32];     // per-wave, per-q partial absmax (4 KB)

    // ---- nontemporal load: all 256 channels for my 4 hw positions ----
    const float* p = in + base;
    f4 v[16];
    #pragma unroll
    for (int it = 0; it < 16; ++it) {
        const int c = it * 16 + crow;
        v[it] = __builtin_nontemporal_load(
                    reinterpret_cast<const f4*>(p + c * HW_));
    }

    // ---- per-thread partial absmax over my 16 channel rows ----
    float m0 = 0.f, m1 = 0.f, m2 = 0.f, m3 = 0.f;
    #pragma unroll
    for (int it = 0; it < 16; ++it) {
        m0 = fmaxf(m0, fabsf(v[it].x));
        m1 = fmaxf(m1, fabsf(v[it].y));
        m2 = fmaxf(m2, fabsf(v[it].z));
        m3 = fmaxf(m3, fabsf(v[it].w));
    }

    // ---- combine the two crows within this wave (lane l <-> l^32, same q) ----
    m0 = fmaxf(m0, __shfl_xor(m0, 32, 64));
    m1 = fmaxf(m1, __shfl_xor(m1, 32, 64));
    m2 = fmaxf(m2, __shfl_xor(m2, 32, 64));
    m3 = fmaxf(m3, __shfl_xor(m3, 32, 64));
    if ((t & 32) == 0) {
        f4 pv; pv.x = m0; pv.y = m1; pv.z = m2; pv.w = m3;
        pw[w][q] = pv;
    }
    __syncthreads();

    // ---- combine the 8 wave partials ----
    f4 a = pw[0][q];
    #pragma unroll
    for (int ww = 1; ww < 8; ++ww) {
        const f4 b2 = pw[ww][q];
        a.x = fmaxf(a.x, b2.x); a.y = fmaxf(a.y, b2.y);
        a.z = fmaxf(a.z, b2.z); a.w = fmaxf(a.w, b2.w);
    }

    float u0, r0, u1, r1, u2, r2, u3, r3;
    po2_scales(a.x, u0, r0);
    po2_scales(a.y, u1, r1);
    po2_scales(a.z, u2, r2);
    po2_scales(a.w, u3, r3);

    // ---- quantize from registers, nontemporal coalesced store ----
    float* po = out + base;
    #pragma unroll
    for (int it = 0; it < 16; ++it) {
        const int c = it * 16 + crow;
        f4 o;
        o.x = fminf(fmaxf(rintf(v[it].x * r0), -7.f), 7.f) * u0;
        o.y = fminf(fmaxf(rintf(v[it].y * r1), -7.f), 7.f) * u1;
        o.z = fminf(fmaxf(rintf(v[it].z * r2), -7.f), 7.f) * u2;
        o.w = fminf(fmaxf(rintf(v[it].w * r3), -7.f), 7.f) * u3;
        __builtin_nontemporal_store(o, reinterpret_cast<f4*>(po + c * HW_));
    }
}

extern "C" void kernel_launch(void* const* d_in, const int* in_sizes, int n_in,
                              void* d_out, int out_size, void* d_ws, size_t ws_size,
                              hipStream_t stream) {
    const float* in = (const float*)d_in[0];
    float* out = (float*)d_out;
    bfp_quant_kernel<<<NBLK, 512, 0, stream>>>(in, out);
}

// Round 7
// 72.257 us; speedup vs baseline: 1.0522x; 1.0522x over previous
//
#include <hip/hip_runtime.h>

// FlexPool BFP quantize: NCHW (64,256,56,56) fp32.
// Per (n,h,w): E = floor(log2(max_c |x|)), ulp = 2^(E-2) (mantissa_bits=3),
// q = clip(rint(x/ulp), -7, 7) * ulp; 0 if the channel block is all-zero.
//
// Streaming, read-once/write-once, nontemporal. B=512 threads, TILE=64 hw
// positions (256 B segments — best measured), v[8] per lane (~60 VGPR) for
// 8 waves/SIMD occupancy. Occupancy-isolation test vs R5 (B=256, v[16]).

#define N_  64
#define C_  256
#define HW_ 3136          // 56*56
#define TILE_ 64          // hw positions per block (= 256 B per channel row)
#define TILES_PER_N (HW_ / TILE_)   // 49

typedef float f4 __attribute__((ext_vector_type(4)));

__device__ __forceinline__ void po2_scales(float amax, float& u, float& r) {
    // u = 2^(E-2), r = 2^(2-E) with E = floor(log2(amax)); 0 if amax == 0.
    u = 0.f; r = 0.f;
    if (amax > 0.f) {
        const int be = (int)(__float_as_uint(amax) >> 23);   // biased exponent
        if (be >= 3) {
            u = __uint_as_float((unsigned)(be - 2) << 23);
            r = __uint_as_float((unsigned)(256 - be) << 23);
        } else {
            // denormal / ultra-tiny amax (unreachable for N(0,1) data)
            const unsigned b2 = __float_as_uint(amax * 0x1.0p+64f);
            const int E = (int)(b2 >> 23) - 191;             // -127 - 64
            u = exp2f((float)(E - 2));
            r = exp2f((float)(2 - E));
        }
    }
}

__global__ __launch_bounds__(512)
void bfp_quant_kernel(const float* __restrict__ in, float* __restrict__ out) {
    const int b    = blockIdx.x;
    const int n    = b / TILES_PER_N;
    const int tile = b - n * TILES_PER_N;
    const int base = n * (C_ * HW_) + tile * TILE_;

    const int t    = threadIdx.x;
    const int q    = t & 15;     // f4 slot -> hw offsets q*4 .. q*4+3
    const int crow = t >> 4;     // 0..31: channel row within each group of 32
    const int w    = t >> 6;     // wave id 0..7

    __shared__ f4 pw[8][16];     // per-wave, per-q partial absmax (2 KB)

    // ---- nontemporal load: all 256 channels for my 4 hw positions ----
    const float* p = in + base + crow * HW_ + q * 4;
    f4 v[8];
    #pragma unroll
    for (int it = 0; it < 8; ++it)
        v[it] = __builtin_nontemporal_load(
                    reinterpret_cast<const f4*>(p + it * (32 * HW_)));

    // ---- per-thread partial absmax over my 8 channel rows ----
    float m0 = 0.f, m1 = 0.f, m2 = 0.f, m3 = 0.f;
    #pragma unroll
    for (int it = 0; it < 8; ++it) {
        m0 = fmaxf(m0, fabsf(v[it].x));
        m1 = fmaxf(m1, fabsf(v[it].y));
        m2 = fmaxf(m2, fabsf(v[it].z));
        m3 = fmaxf(m3, fabsf(v[it].w));
    }

    // ---- wave-internal reduce across the 4 lanes sharing this q (bits 4,5) ----
    #pragma unroll
    for (int mask = 16; mask <= 32; mask <<= 1) {
        m0 = fmaxf(m0, __shfl_xor(m0, mask, 64));
        m1 = fmaxf(m1, __shfl_xor(m1, mask, 64));
        m2 = fmaxf(m2, __shfl_xor(m2, mask, 64));
        m3 = fmaxf(m3, __shfl_xor(m3, mask, 64));
    }
    if ((t & 48) == 0) {
        f4 pv; pv.x = m0; pv.y = m1; pv.z = m2; pv.w = m3;
        pw[w][q] = pv;
    }
    __syncthreads();

    // ---- combine the 8 wave partials (broadcast LDS reads) ----
    f4 a = pw[0][q];
    #pragma unroll
    for (int ww = 1; ww < 8; ++ww) {
        const f4 bb = pw[ww][q];
        a.x = fmaxf(a.x, bb.x); a.y = fmaxf(a.y, bb.y);
        a.z = fmaxf(a.z, bb.z); a.w = fmaxf(a.w, bb.w);
    }

    float u0, r0, u1, r1, u2, r2, u3, r3;
    po2_scales(a.x, u0, r0);
    po2_scales(a.y, u1, r1);
    po2_scales(a.z, u2, r2);
    po2_scales(a.w, u3, r3);

    // ---- quantize from registers, nontemporal coalesced store ----
    float* po = out + base + crow * HW_ + q * 4;
    #pragma unroll
    for (int it = 0; it < 8; ++it) {
        f4 o;
        o.x = fminf(fmaxf(rintf(v[it].x * r0), -7.f), 7.f) * u0;
        o.y = fminf(fmaxf(rintf(v[it].y * r1), -7.f), 7.f) * u1;
        o.z = fminf(fmaxf(rintf(v[it].z * r2), -7.f), 7.f) * u2;
        o.w = fminf(fmaxf(rintf(v[it].w * r3), -7.f), 7.f) * u3;
        __builtin_nontemporal_store(o,
            reinterpret_cast<f4*>(po + it * (32 * HW_)));
    }
}

extern "C" void kernel_launch(void* const* d_in, const int* in_sizes, int n_in,
                              void* d_out, int out_size, void* d_ws, size_t ws_size,
                              hipStream_t stream) {
    const float* in = (const float*)d_in[0];
    float* out = (float*)d_out;
    const int grid = N_ * TILES_PER_N;   // 64*49 = 3136 blocks
    bfp_quant_kernel<<<grid, 512, 0, stream>>>(in, out);
}